// Round 11
// baseline (130.016 us; speedup 1.0000x reference)
//
#include <hip/hip_runtime.h>
#include <math.h>

#define NN 16384
#define T 512

typedef float f2 __attribute__((ext_vector_type(2)));
typedef float f4 __attribute__((ext_vector_type(4)));

__device__ __forceinline__ f2 elu2(f2 v) {
    f2 e;
    e.x = __expf(v.x);
    e.y = __expf(v.y);
    const f2 zero = (f2)0.0f;
    return __builtin_elementwise_max(v, zero)
         + __builtin_elementwise_min(e - 1.0f, zero);
}

// ---- setup: composite 9-tap weights cw[6][9] = conv1 ∘ [deriv ; I - box] ----
__global__ void smag_setup(const float* __restrict__ dw,
                           const float* __restrict__ fw,
                           const float* __restrict__ W1,
                           float* __restrict__ cw)
{
    const int t = threadIdx.x;
    if (t < 54) {
        const int c = t / 9;
        const int m = (t % 9) - 4;
        float acc = 0.0f;
        #pragma unroll
        for (int k = 0; k < 5; ++k) {
            int j = m + 4 - k;
            if (j >= 0 && j <= 4) acc += W1[c * 10 + k] * dw[j];
        }
        if (m >= -2 && m <= 2) acc += W1[c * 10 + 5 + (m + 2)];
        #pragma unroll
        for (int i = 0; i < 3; ++i) {
            int k = m + 3 - i;
            if (k >= 0 && k <= 4) acc -= fw[i] * W1[c * 10 + 5 + k];
        }
        cw[t] = acc;
    }
}

__global__ __launch_bounds__(128, 4)
void smag_q4(const float* __restrict__ x,
             const float* __restrict__ dw,
             const float* __restrict__ cw,    // [6][9] composite
             const float* __restrict__ b1,
             const float* __restrict__ W2, const float* __restrict__ b2,
             const float* __restrict__ W3, const float* __restrict__ b3,
             float* __restrict__ out)
{
    const int blk = blockIdx.x & 31;        // 32 tiles per row
    const int row = blockIdx.x >> 5;
    const int tb  = blk * T;
    const int tid = threadIdx.x;            // 128 threads, 4 outputs each
    const float* __restrict__ xr = x   + (size_t)row * NN;
    float* __restrict__ outr     = out + (size_t)row * NN;

    // Aliased arena: 4704 floats = 18.8 KB -> 8 blocks/CU.
    //   sh1 [0,3144)    live S2..S3   | sy [0,516) live S4..S5 (sh1 dead)
    //   sh2 [3144,4704) live S3..S4
    __shared__ __align__(16) float sm[4704];
    float* const sh1 = sm;          // [6][524] h1 : idx = c*524 + pos + 6, pos in [-6,518)
    float* const sy  = sm;          // y  : idx = pos + 2, pos in [-2,514)
    float* const sh2 = sm + 3144;   // [3][520] h2 : idx = c*520 + pos + 4, pos in [-4,516)

    const float d0 = dw[0], d1 = dw[1], d2 = dw[2], d3 = dw[3], d4 = dw[4];

    // ---- S2': h1 quad at [p,p+4) = elu(conv9(x,cw)+b1); also xd pairs at p+4, p+6 ----
    f2 xd0_m, xd1_m, xd0_t, xd1_t;
    auto S2p = [&](int p, f2& xd0, f2& xd1) {
        f2 G[7];
        #pragma unroll
        for (int i = 0; i < 7; ++i) {
            int g = (tb + p - 4 + 2 * i + NN) & (NN - 1);
            G[i] = *(const f2*)(xr + g);
        }
        f2 o[6];
        #pragma unroll
        for (int i = 0; i < 6; ++i) o[i] = (f2){G[i].y, G[i + 1].x};
        #pragma unroll
        for (int c = 0; c < 6; ++c) {
            const float* w = cw + c * 9;
            f2 a0 = (f2)b1[c];
            f2 a1 = a0;
            #pragma unroll
            for (int k = 0; k < 5; ++k) {          // even taps m=2k-4
                a0 = a0 + G[k] * w[2 * k];
                a1 = a1 + G[k + 1] * w[2 * k];
            }
            #pragma unroll
            for (int k = 0; k < 4; ++k) {          // odd taps m=2k-3
                a0 = a0 + o[k] * w[2 * k + 1];
                a1 = a1 + o[k + 1] * w[2 * k + 1];
            }
            f2 e0 = elu2(a0), e1 = elu2(a1);
            *(f4*)(sh1 + c * 524 + p + 6) = (f4){e0.x, e0.y, e1.x, e1.y};
        }
        // xd at pairs (p+4,p+5) and (p+6,p+7)
        xd0 = G[3] * d0 + o[3] * d1 + G[4] * d2 + o[4] * d3 + G[5] * d4;
        xd1 = G[4] * d0 + o[4] * d1 + G[5] * d2 + o[5] * d3 + G[6] * d4;
    };
    S2p(4 * tid - 6, xd0_m, xd1_m);
    if (tid < 3) S2p(506 + 4 * tid, xd0_t, xd1_t);
    __syncthreads();

    // ---- S3: h2 quad at [q,q+4) = elu(conv5(h1,W2)+b2) ----
    auto S3 = [&](int q) {
        f2 ac0[3], ac1[3];
        #pragma unroll
        for (int oc = 0; oc < 3; ++oc) { ac0[oc] = (f2)b2[oc]; ac1[oc] = ac0[oc]; }
        #pragma unroll
        for (int ci = 0; ci < 6; ++ci) {
            const float* hb = sh1 + ci * 524 + q + 4;   // h1[ci] at pos q-2
            f4 A = *(const f4*)(hb);
            f4 B = *(const f4*)(hb + 4);
            f2 w0 = {A.x, A.y}, w1 = {A.y, A.z}, w2 = {A.z, A.w};
            f2 w3 = {A.w, B.x}, w4 = {B.x, B.y}, w5 = {B.y, B.z}, w6 = {B.z, B.w};
            #pragma unroll
            for (int oc = 0; oc < 3; ++oc) {
                const float* ww = W2 + oc * 30 + ci * 5;
                ac0[oc] = ac0[oc] + w0 * ww[0] + w1 * ww[1] + w2 * ww[2] + w3 * ww[3] + w4 * ww[4];
                ac1[oc] = ac1[oc] + w2 * ww[0] + w3 * ww[1] + w4 * ww[2] + w5 * ww[3] + w6 * ww[4];
            }
        }
        #pragma unroll
        for (int oc = 0; oc < 3; ++oc) {
            f2 e0 = elu2(ac0[oc]), e1 = elu2(ac1[oc]);
            *(f4*)(sh2 + oc * 520 + q + 4) = (f4){e0.x, e0.y, e1.x, e1.y};
        }
    };
    S3(4 * tid - 4);
    if (tid < 2) S3(508 + 4 * tid);
    __syncthreads();

    // ---- S4: y quad at [q,q+4); clip(elu(a),0,1)==clamp(a,0,1); K=sqrt2*CUT^2 ----
    const float B3v = b3[0];
    const float K = 1.41421356237309515f * (float)(2.0/16384.0) * (float)(2.0/16384.0);
    auto S4 = [&](int q, f2 xd0, f2 xd1) {
        f2 a0 = (f2)B3v, a1 = a0;
        #pragma unroll
        for (int ci = 0; ci < 3; ++ci) {
            const float* hb = sh2 + ci * 520 + q + 2;   // h2[ci] at pos q-2
            f4 A = *(const f4*)(hb);
            f4 B = *(const f4*)(hb + 4);
            f2 w0 = {A.x, A.y}, w1 = {A.y, A.z}, w2 = {A.z, A.w};
            f2 w3 = {A.w, B.x}, w4 = {B.x, B.y}, w5 = {B.y, B.z}, w6 = {B.z, B.w};
            const float* ww = W3 + ci * 5;
            a0 = a0 + w0 * ww[0] + w1 * ww[1] + w2 * ww[2] + w3 * ww[3] + w4 * ww[4];
            a1 = a1 + w2 * ww[0] + w3 * ww[1] + w4 * ww[2] + w5 * ww[3] + w6 * ww[4];
        }
        const f2 zero = (f2)0.0f, one = (f2)1.0f;
        f2 c0 = __builtin_elementwise_min(__builtin_elementwise_max(a0, zero), one);
        f2 c1 = __builtin_elementwise_min(__builtin_elementwise_max(a1, zero), one);
        f2 y0 = (c0 * c0) * (__builtin_elementwise_abs(xd0) * xd0) * K;
        f2 y1 = (c1 * c1) * (__builtin_elementwise_abs(xd1) * xd1) * K;
        *(f4*)(sy + q + 2) = (f4){y0.x, y0.y, y1.x, y1.y};
    };
    S4(4 * tid - 2, xd0_m, xd1_m);
    if (tid < 1) S4(510 + 4 * tid, xd0_t, xd1_t);
    __syncthreads();

    // ---- S5: out quad at [p,p+4) = conv5(y,dw), b128 store ----
    {
        const int p = 4 * tid;
        f4 A = *(const f4*)(sy + p);       // y[p-2..p+2)
        f4 B = *(const f4*)(sy + p + 4);   // y[p+2..p+6)
        f2 w0 = {A.x, A.y}, w1 = {A.y, A.z}, w2 = {A.z, A.w};
        f2 w3 = {A.w, B.x}, w4 = {B.x, B.y}, w5 = {B.y, B.z}, w6 = {B.z, B.w};
        f2 o0 = w0 * d0 + w1 * d1 + w2 * d2 + w3 * d3 + w4 * d4;
        f2 o1 = w2 * d0 + w3 * d1 + w4 * d2 + w5 * d3 + w6 * d4;
        *(f4*)(outr + tb + p) = (f4){o0.x, o0.y, o1.x, o1.y};
    }
}

extern "C" void kernel_launch(void* const* d_in, const int* in_sizes, int n_in,
                              void* d_out, int out_size, void* d_ws, size_t ws_size,
                              hipStream_t stream) {
    const float* x  = (const float*)d_in[0];
    const float* dw = (const float*)d_in[1];
    const float* fw = (const float*)d_in[2];
    const float* W1 = (const float*)d_in[3];
    const float* b1 = (const float*)d_in[4];
    const float* W2 = (const float*)d_in[5];
    const float* b2 = (const float*)d_in[6];
    const float* W3 = (const float*)d_in[7];
    const float* b3 = (const float*)d_in[8];
    float* out = (float*)d_out;
    float* cw  = (float*)d_ws;   // 54 floats

    hipLaunchKernelGGL(smag_setup, dim3(1), dim3(64), 0, stream, dw, fw, W1, cw);

    const int B = 1024;
    dim3 grid(B * (NN / T));    // 32768 blocks
    dim3 block(128);
    hipLaunchKernelGGL(smag_q4, grid, block, 0, stream,
                       x, dw, cw, b1, W2, b2, W3, b3, out);
}

// Round 12
// 97.203 us; speedup vs baseline: 1.3376x; 1.3376x over previous
//
#include <hip/hip_runtime.h>
#include <math.h>

#define NN 16384
#define T 500
#define TILES 33   // ceil(16384/500); wrap tile duplicates are bitwise-identical

typedef float f2 __attribute__((ext_vector_type(2)));

__device__ __forceinline__ f2 elu2(f2 v) {
    f2 e;
    e.x = __expf(v.x);
    e.y = __expf(v.y);
    const f2 zero = (f2)0.0f;
    return __builtin_elementwise_max(v, zero)
         + __builtin_elementwise_min(e - 1.0f, zero);
}

// ---- setup: composite 9-tap weights cw[6][9] = conv1 ∘ [deriv ; I - box] ----
__global__ void smag_setup(const float* __restrict__ dw,
                           const float* __restrict__ fw,
                           const float* __restrict__ W1,
                           float* __restrict__ cw)
{
    const int t = threadIdx.x;
    if (t < 54) {
        const int c = t / 9;
        const int m = (t % 9) - 4;
        float acc = 0.0f;
        #pragma unroll
        for (int k = 0; k < 5; ++k) {
            int j = m + 4 - k;
            if (j >= 0 && j <= 4) acc += W1[c * 10 + k] * dw[j];
        }
        if (m >= -2 && m <= 2) acc += W1[c * 10 + 5 + (m + 2)];
        #pragma unroll
        for (int i = 0; i < 3; ++i) {
            int k = m + 3 - i;
            if (k >= 0 && k <= 4) acc -= fw[i] * W1[c * 10 + 5 + k];
        }
        cw[t] = acc;
    }
}

__global__ __launch_bounds__(256, 8)
void smag_t5(const float* __restrict__ x,
             const float* __restrict__ dw,
             const float* __restrict__ cw,    // [6][9] composite
             const float* __restrict__ b1,
             const float* __restrict__ W2, const float* __restrict__ b2,
             const float* __restrict__ W3, const float* __restrict__ b3,
             float* __restrict__ out)
{
    const int blk = (int)(blockIdx.x % TILES);
    const int row = (int)(blockIdx.x / TILES);
    const int tb  = blk * T;
    const int tid = threadIdx.x;
    const float* __restrict__ xr = x   + (size_t)row * NN;
    float* __restrict__ outr     = out + (size_t)row * NN;

    // Aliased arena: 4608 floats = 18.4 KB -> 8 blocks/CU.
    //   sh1 [0,3072)    live S2..S3   | sy [0,504) live S4..S5 (sh1 dead)
    //   sh2 [3072,4608) live S3..S4
    __shared__ __align__(16) float sm[4608];
    float* const sh1 = sm;          // [6][512] h1 : idx = c*512 + pos + 6, pos in [-6,506)
    float* const sy  = sm;          // y  : idx = pos + 2, pos in [-2,502)
    float* const sh2 = sm + 3072;   // [3][512] h2 : idx = c*512 + pos + 4, pos in [-4,504)

    const float d0 = dw[0], d1 = dw[1], d2 = dw[2], d3 = dw[3], d4 = dw[4];

    // ---- S2': h1 pair at p = 2*tid-6 (exactly 256 pairs, no tail); xd at p+4 ----
    f2 xd_m;
    {
        const int p = 2 * tid - 6;
        f2 G[6];
        #pragma unroll
        for (int i = 0; i < 6; ++i) {
            int g = (tb + p - 4 + 2 * i + NN) & (NN - 1);
            G[i] = *(const f2*)(xr + g);
        }
        f2 w9[9] = {G[0], {G[0].y, G[1].x}, G[1], {G[1].y, G[2].x}, G[2],
                    {G[2].y, G[3].x}, G[3], {G[3].y, G[4].x}, G[4]};
        #pragma unroll
        for (int c = 0; c < 6; ++c) {
            f2 a = (f2)b1[c];
            #pragma unroll
            for (int m = 0; m < 9; ++m)
                a = a + w9[m] * cw[c * 9 + m];
            *(f2*)(sh1 + c * 512 + p + 6) = elu2(a);
        }
        f2 a12 = {G[3].y, G[4].x};
        f2 a34 = {G[4].y, G[5].x};
        xd_m = G[3] * d0 + a12 * d1 + G[4] * d2 + a34 * d3 + G[5] * d4;
    }
    __syncthreads();

    // ---- S3: h2 pair at q = 2*tid-4 (254 pairs, single pass) ----
    if (tid < 254) {
        const int q = 2 * tid - 4;
        f2 acc0 = (f2)b2[0], acc1 = (f2)b2[1], acc2 = (f2)b2[2];
        #pragma unroll
        for (int ci = 0; ci < 6; ++ci) {
            const float* hb = sh1 + ci * 512 + q + 4;   // h1[ci] at q-2
            f2 H0 = *(f2*)(hb);
            f2 H1 = *(f2*)(hb + 2);
            f2 H2 = *(f2*)(hb + 4);
            f2 ha[5] = {H0, {H0.y, H1.x}, H1, {H1.y, H2.x}, H2};
            #pragma unroll
            for (int k = 0; k < 5; ++k) {
                acc0 = acc0 + ha[k] * W2[0 * 30 + ci * 5 + k];
                acc1 = acc1 + ha[k] * W2[1 * 30 + ci * 5 + k];
                acc2 = acc2 + ha[k] * W2[2 * 30 + ci * 5 + k];
            }
        }
        *(f2*)(sh2 + 0 * 512 + q + 4) = elu2(acc0);
        *(f2*)(sh2 + 1 * 512 + q + 4) = elu2(acc1);
        *(f2*)(sh2 + 2 * 512 + q + 4) = elu2(acc2);
    }
    __syncthreads();

    // ---- S4: y pair at q = 2*tid-2 (252 pairs); clip(elu(a),0,1)==clamp(a,0,1) ----
    const float B3v = b3[0];
    const float K = 1.41421356237309515f * (float)(2.0/16384.0) * (float)(2.0/16384.0);
    if (tid < 252) {
        const int q = 2 * tid - 2;
        f2 a = (f2)B3v;
        #pragma unroll
        for (int ci = 0; ci < 3; ++ci) {
            const float* hb = sh2 + ci * 512 + q + 2;   // h2[ci] at q-2
            f2 H0 = *(f2*)(hb);
            f2 H1 = *(f2*)(hb + 2);
            f2 H2 = *(f2*)(hb + 4);
            f2 ha1 = {H0.y, H1.x};
            f2 ha3 = {H1.y, H2.x};
            a = a + H0 * W3[ci * 5 + 0] + ha1 * W3[ci * 5 + 1] + H1 * W3[ci * 5 + 2]
                  + ha3 * W3[ci * 5 + 3] + H2 * W3[ci * 5 + 4];
        }
        f2 cs = __builtin_elementwise_min(__builtin_elementwise_max(a, (f2)0.0f), (f2)1.0f);
        f2 axd = __builtin_elementwise_abs(xd_m);
        f2 y = (cs * cs) * (axd * xd_m) * K;
        *(f2*)(sy + q + 2) = y;
    }
    __syncthreads();

    // ---- S5: out pair at s = 2*tid (250 pairs), wrap-store (duplicates identical) ----
    if (tid < 250) {
        const int s = 2 * tid;
        f2 Y0 = *(f2*)(sy + s);          // y[s-2], y[s-1]
        f2 Y1 = *(f2*)(sy + s + 2);      // y[s],   y[s+1]
        f2 Y2 = *(f2*)(sy + s + 4);      // y[s+2], y[s+3]
        f2 a12 = {Y0.y, Y1.x};
        f2 a34 = {Y1.y, Y2.x};
        f2 o = Y0 * d0 + a12 * d1 + Y1 * d2 + a34 * d3 + Y2 * d4;
        *(f2*)(outr + ((tb + s) & (NN - 1))) = o;
    }
}

extern "C" void kernel_launch(void* const* d_in, const int* in_sizes, int n_in,
                              void* d_out, int out_size, void* d_ws, size_t ws_size,
                              hipStream_t stream) {
    const float* x  = (const float*)d_in[0];
    const float* dw = (const float*)d_in[1];
    const float* fw = (const float*)d_in[2];
    const float* W1 = (const float*)d_in[3];
    const float* b1 = (const float*)d_in[4];
    const float* W2 = (const float*)d_in[5];
    const float* b2 = (const float*)d_in[6];
    const float* W3 = (const float*)d_in[7];
    const float* b3 = (const float*)d_in[8];
    float* out = (float*)d_out;
    float* cw  = (float*)d_ws;   // 54 floats

    hipLaunchKernelGGL(smag_setup, dim3(1), dim3(64), 0, stream, dw, fw, W1, cw);

    const int B = 1024;
    dim3 grid(B * TILES);       // 33792 blocks
    dim3 block(256);
    hipLaunchKernelGGL(smag_t5, grid, block, 0, stream,
                       x, dw, cw, b1, W2, b2, W3, b3, out);
}